// Round 8
// baseline (759.919 us; speedup 1.0000x reference)
//
#include <hip/hip_runtime.h>
#include <hip/hip_cooperative_groups.h>

// ---------------------------------------------------------------------------
// SpatialSatCrossAttention — SINGLE cooperative kernel, grid.sync() between
// stages (R7 showed ~100us of dispatch-boundary cost across 5 launches).
// Stages (grid-stride, one launch):
//   P  : value->bf16, query->bf16, weights -> Wt[n][k] bf16
//   G1 : vproj = value_bf @ value_W + b (bf16)  AND
//        qkcat = query_bf @ [off|attw]_W + b (bf16)   [64x64 MFMA tiles]
//   S  : deformable bilinear sampling -> slots bf16   [R7-proven core]
//   G2 : out = slots @ out_W + out_b + query (f32 d_out)
// Fused kernel kept at VGPR<=128 (launch_bounds(256,4)), LDS 16.4 KB union,
// so the sample stage keeps ~16 waves/CU.
// ---------------------------------------------------------------------------

typedef unsigned short ushort_t;
typedef unsigned int uint_t;
typedef __attribute__((ext_vector_type(8))) short bf16x8;
typedef __attribute__((ext_vector_type(4))) float f32x4;
typedef __attribute__((ext_vector_type(2))) float f32x2;

__device__ __forceinline__ float bf2f(ushort_t u) {
    return __uint_as_float(((uint_t)u) << 16);
}
__device__ __forceinline__ ushort_t f2bf(float f) {
    uint_t i = __float_as_uint(f);
    uint_t r = i + 0x7fffu + ((i >> 16) & 1u);   // round-to-nearest-even
    return (ushort_t)(r >> 16);
}

struct GemmSmem  { ushort_t sA[2][64][32]; ushort_t sB[2][64][32]; };  // 16 KB
struct SampleSmem {
    float valid[8];
    int   ci[4][256];
    float cw[4][256];
    float red[256][8];
};                                                                      // 16.4 KB
struct PrepSmem  { float tile[32][33]; };                               // 4.2 KB
union SmemAll { GemmSmem g; SampleSmem s; PrepSmem p; };

// ---------------------------------------------------------------------------
// Stage P unit: u<4080 value cvt, u<5330 query cvt, else weight transpose.
// ---------------------------------------------------------------------------
__device__ __forceinline__ void prep_unit(
    int u, PrepSmem* sp,
    const float* __restrict__ value, const float* __restrict__ query,
    const float* __restrict__ Wv, const float* __restrict__ Wo,
    const float* __restrict__ Wf, const float* __restrict__ Wa,
    ushort_t* __restrict__ value_bf, ushort_t* __restrict__ query_bf,
    ushort_t* __restrict__ Tv, ushort_t* __restrict__ To,
    ushort_t* __restrict__ Tqk) {
    const int tid = threadIdx.x;
    if (u < 5330) {
        const float* src;
        ushort_t* dst;
        int i, n8;
        if (u < 4080) { src = value; dst = value_bf; i = u * 256 + tid;          n8 = 1044480; }
        else          { src = query; dst = query_bf; i = (u - 4080) * 256 + tid; n8 = 320000; }
        if (i >= n8) return;
        const float4 v0 = *(const float4*)(src + (size_t)i * 8);
        const float4 v1 = *(const float4*)(src + (size_t)i * 8 + 4);
        const bf16x8 pk = {
            (short)f2bf(v0.x), (short)f2bf(v0.y), (short)f2bf(v0.z), (short)f2bf(v0.w),
            (short)f2bf(v1.x), (short)f2bf(v1.y), (short)f2bf(v1.z), (short)f2bf(v1.w)};
        *(bf16x8*)(dst + (size_t)i * 8) = pk;
        return;
    }
    const int b2 = u - 5330;
    const int z   = b2 >> 7;
    const int rem = b2 & 127;
    const int k0 = (rem & 7) * 32;
    const int n0 = (rem >> 3) * 32;
    const float* W;
    ushort_t* T;
    int N;
    if (z == 0)      { W = Wv; T = Tv;              N = 256; }
    else if (z == 1) { W = Wo; T = To;              N = 256; }
    else if (z == 2) { W = Wf; T = Tqk;             N = 512; }
    else             { W = Wa; T = Tqk + 512 * 256; N = 256; }
    if (n0 >= N) return;

    const int tx = tid & 31;
    const int ty = tid >> 5;   // 0..7
    #pragma unroll
    for (int r = 0; r < 4; ++r) {
        const int k = ty + r * 8;
        sp->tile[k][tx] = W[(size_t)(k0 + k) * N + n0 + tx];
    }
    __syncthreads();
    #pragma unroll
    for (int r = 0; r < 4; ++r) {
        const int n = ty + r * 8;
        T[(size_t)(n0 + n) * 256 + k0 + tx] = f2bf(sp->tile[tx][n]);
    }
    __syncthreads();   // LDS safe for next grid-stride unit
}

// ---------------------------------------------------------------------------
// 64x64 MFMA GEMM tile: C[M,N] = A[M,256] @ Wt^T + bias (+resid).
// 4 waves, each owns 16 rows x 64 cols (4 mfma_16x16x32 / K-step).
// Double-buffered LDS + register prefetch. N multiple of 64.
// ---------------------------------------------------------------------------
template <bool OUT_BF16, bool RESID>
__device__ __forceinline__ void gemm64_tile(
    GemmSmem* sm,
    const ushort_t* __restrict__ A, const ushort_t* __restrict__ Wt,
    const float* __restrict__ bias0, const float* __restrict__ bias1, int split,
    const float* __restrict__ resid, void* __restrict__ Cv,
    int M, int N, int u) {
    const int tn = N >> 6;
    const int bx = u / tn;
    const int by = u - bx * tn;
    const int m0 = bx << 6, n0 = by << 6;
    const int t = threadIdx.x, lane = t & 63, w = t >> 6;
    const int srow = t >> 2;          // 0..63
    const int skof = (t & 3) << 3;    // 0,8,16,24
    const bool am = (m0 + srow) < M;
    const ushort_t* Ap = A + (size_t)(m0 + srow) * 256 + skof;
    const ushort_t* Bp = Wt + (size_t)(n0 + srow) * 256 + skof;
    const bf16x8 zz = {0, 0, 0, 0, 0, 0, 0, 0};

    f32x4 acc[4];
    #pragma unroll
    for (int j = 0; j < 4; ++j) acc[j] = (f32x4){0.f, 0.f, 0.f, 0.f};

    *(bf16x8*)(&sm->sA[0][srow][skof]) = am ? *(const bf16x8*)Ap : zz;
    *(bf16x8*)(&sm->sB[0][srow][skof]) = *(const bf16x8*)Bp;
    __syncthreads();

    const int rl = lane & 15;
    const int kq = (lane >> 4) << 3;

    for (int k = 0; k < 8; ++k) {
        const int buf = k & 1;
        bf16x8 na = zz, nb = zz;
        if (k < 7) {
            const int ko = (k + 1) << 5;
            if (am) na = *(const bf16x8*)(Ap + ko);
            nb = *(const bf16x8*)(Bp + ko);
        }
        const bf16x8 af = *(const bf16x8*)(&sm->sA[buf][(w << 4) + rl][kq]);
        bf16x8 bfr[4];
        #pragma unroll
        for (int j = 0; j < 4; ++j)
            bfr[j] = *(const bf16x8*)(&sm->sB[buf][(j << 4) + rl][kq]);
        #pragma unroll
        for (int j = 0; j < 4; ++j)
            acc[j] = __builtin_amdgcn_mfma_f32_16x16x32_bf16(af, bfr[j], acc[j], 0, 0, 0);
        if (k < 7) {
            __syncthreads();
            *(bf16x8*)(&sm->sA[buf ^ 1][srow][skof]) = na;
            *(bf16x8*)(&sm->sB[buf ^ 1][srow][skof]) = nb;
            __syncthreads();
        }
    }

    // epilogue: C/D layout col=lane&15, row=(lane>>4)*4+reg (m89)
    const int col_l = lane & 15;
    const int rq = (lane >> 4) << 2;
    #pragma unroll
    for (int j = 0; j < 4; ++j) {
        const int gn = n0 + (j << 4) + col_l;
        const float bj = (gn < split) ? bias0[gn] : bias1[gn - split];
        #pragma unroll
        for (int r = 0; r < 4; ++r) {
            const int gm = m0 + (w << 4) + rq + r;
            if (gm >= M) continue;
            float v = acc[j][r] + bj;
            if (RESID) v += resid[(size_t)gm * N + gn];
            if (OUT_BF16)
                ((ushort_t*)Cv)[(size_t)gm * N + gn] = f2bf(v);
            else
                ((float*)Cv)[(size_t)gm * N + gn] = v;
        }
    }
}

// ---------------------------------------------------------------------------
// Sample stage (R7-proven core). qkcat is bf16 [10000][768].
// ---------------------------------------------------------------------------
__device__ __forceinline__ void sample_unit(
    int q, SampleSmem* ss,
    const ushort_t* __restrict__ qkcat, const float* __restrict__ refp,
    const int* __restrict__ vox, const ushort_t* __restrict__ vproj,
    ushort_t* __restrict__ slots) {
    const int tid = threadIdx.x;
    const int h     = tid >> 5;
    const int lp    = tid & 31;
    const int slice = (tid >> 2) & 7;
    const int g     = tid & 3;

    if (tid < 6) {
        const int base = (tid * 10000 + q) * 4;
        const int mm = vox[base] | vox[base + 1] | vox[base + 2] | vox[base + 3];
        ss->valid[tid] = mm ? 1.0f : 0.0f;
    }

    // softmax over 32 (lvl,p) per head (32-lane group)
    const float a = bf2f(qkcat[(size_t)q * 768 + 512 + tid]);
    float mx = a;
    #pragma unroll
    for (int o = 16; o >= 1; o >>= 1) mx = fmaxf(mx, __shfl_xor(mx, o));
    const float e = __expf(a - mx);
    float se = e;
    #pragma unroll
    for (int o = 16; o >= 1; o >>= 1) se += __shfl_xor(se, o);
    const float aw = e / se;

    const int lvl = lp >> 3;
    const int p   = lp & 7;
    const int dd  = p & 3;
    const int   Sarr[4]   = {64, 32, 16, 8};
    const int   Lstart[4] = {0, 4096, 5120, 5376};
    const int   S  = Sarr[lvl];
    const float Sf = (float)S;
    const float invSf = 1.0f / Sf;     // exact (pow2)
    const int   lstart = Lstart[lvl];
    const float ox = bf2f(qkcat[(size_t)q * 768 + h * 64 + lvl * 16 + p * 2 + 0]) * invSf;
    const float oy = bf2f(qkcat[(size_t)q * 768 + h * 64 + lvl * 16 + p * 2 + 1]) * invSf;

    __syncthreads();
    const float cnt = ss->valid[0] + ss->valid[1] + ss->valid[2] +
                      ss->valid[3] + ss->valid[4] + ss->valid[5];

    f32x2 acc2[4] = {{0.f, 0.f}, {0.f, 0.f}, {0.f, 0.f}, {0.f, 0.f}};
    const ushort_t* vp = vproj + (g << 3);

    for (int c = 0; c < 6; ++c) {
        if (ss->valid[c] == 0.0f) continue;   // block-uniform

        {
            const int rbase = ((c * 10000 + q) * 4 + dd) * 2;
            const float rx = refp[rbase + 0];
            const float ry = refp[rbase + 1];
            const float x  = (rx + ox) * Sf - 0.5f;
            const float y  = (ry + oy) * Sf - 0.5f;
            const float x0 = floorf(x), y0 = floorf(y);
            #pragma unroll
            for (int k = 0; k < 4; ++k) {
                const float cx = x0 + (float)(k & 1);
                const float cy = y0 + (float)(k >> 1);
                const float wgt = (1.0f - fabsf(x - cx)) * (1.0f - fabsf(y - cy));
                const bool ok = (cx >= 0.0f) & (cx < Sf) & (cy >= 0.0f) & (cy < Sf);
                const int xi = (int)fminf(fmaxf(cx, 0.0f), Sf - 1.0f);
                const int yi = (int)fminf(fmaxf(cy, 0.0f), Sf - 1.0f);
                ss->ci[k][tid] = (c * 5440 + lstart + yi * S + xi) * 256 + h * 32;
                ss->cw[k][tid] = ok ? wgt * aw : 0.0f;
            }
        }
        __syncthreads();

        #pragma unroll
        for (int j = 0; j < 4; ++j) {
            const int el = h * 32 + slice * 4 + j;
            const int i0 = ss->ci[0][el], i1 = ss->ci[1][el];
            const int i2 = ss->ci[2][el], i3 = ss->ci[3][el];
            const float w0 = ss->cw[0][el], w1 = ss->cw[1][el];
            const float w2 = ss->cw[2][el], w3 = ss->cw[3][el];
            const uint4 v0 = *(const uint4*)(vp + i0);
            const uint4 v1 = *(const uint4*)(vp + i1);
            const uint4 v2 = *(const uint4*)(vp + i2);
            const uint4 v3 = *(const uint4*)(vp + i3);
            const f32x2 W0 = {w0, w0}, W1 = {w1, w1}, W2 = {w2, w2}, W3 = {w3, w3};
            acc2[0] += W0 * (f32x2){__uint_as_float(v0.x << 16), __uint_as_float(v0.x & 0xffff0000u)};
            acc2[1] += W0 * (f32x2){__uint_as_float(v0.y << 16), __uint_as_float(v0.y & 0xffff0000u)};
            acc2[2] += W0 * (f32x2){__uint_as_float(v0.z << 16), __uint_as_float(v0.z & 0xffff0000u)};
            acc2[3] += W0 * (f32x2){__uint_as_float(v0.w << 16), __uint_as_float(v0.w & 0xffff0000u)};
            acc2[0] += W1 * (f32x2){__uint_as_float(v1.x << 16), __uint_as_float(v1.x & 0xffff0000u)};
            acc2[1] += W1 * (f32x2){__uint_as_float(v1.y << 16), __uint_as_float(v1.y & 0xffff0000u)};
            acc2[2] += W1 * (f32x2){__uint_as_float(v1.z << 16), __uint_as_float(v1.z & 0xffff0000u)};
            acc2[3] += W1 * (f32x2){__uint_as_float(v1.w << 16), __uint_as_float(v1.w & 0xffff0000u)};
            acc2[0] += W2 * (f32x2){__uint_as_float(v2.x << 16), __uint_as_float(v2.x & 0xffff0000u)};
            acc2[1] += W2 * (f32x2){__uint_as_float(v2.y << 16), __uint_as_float(v2.y & 0xffff0000u)};
            acc2[2] += W2 * (f32x2){__uint_as_float(v2.z << 16), __uint_as_float(v2.z & 0xffff0000u)};
            acc2[3] += W2 * (f32x2){__uint_as_float(v2.w << 16), __uint_as_float(v2.w & 0xffff0000u)};
            acc2[0] += W3 * (f32x2){__uint_as_float(v3.x << 16), __uint_as_float(v3.x & 0xffff0000u)};
            acc2[1] += W3 * (f32x2){__uint_as_float(v3.y << 16), __uint_as_float(v3.y & 0xffff0000u)};
            acc2[2] += W3 * (f32x2){__uint_as_float(v3.z << 16), __uint_as_float(v3.z & 0xffff0000u)};
            acc2[3] += W3 * (f32x2){__uint_as_float(v3.w << 16), __uint_as_float(v3.w & 0xffff0000u)};
        }
        __syncthreads();
    }

    #pragma unroll
    for (int n = 0; n < 4; ++n) {
        ss->red[tid][2 * n]     = acc2[n].x;
        ss->red[tid][2 * n + 1] = acc2[n].y;
    }
    __syncthreads();

    const int cch = tid & 31;
    float sum = 0.0f;
    #pragma unroll
    for (int s = 0; s < 8; ++s)
        sum += ss->red[h * 32 + s * 4 + (cch >> 3)][cch & 7];

    slots[(size_t)q * 256 + tid] = f2bf(sum / fmaxf(cnt, 1.0f));
}

// ---------------------------------------------------------------------------
// The fused cooperative kernel.
// ---------------------------------------------------------------------------
__global__ __launch_bounds__(256, 4) void fused_k(
    const float* __restrict__ query, const float* __restrict__ value,
    const float* __restrict__ refp, const int* __restrict__ vox,
    const float* __restrict__ value_W, const float* __restrict__ value_b,
    const float* __restrict__ off_W, const float* __restrict__ off_b,
    const float* __restrict__ attw_W, const float* __restrict__ attw_b,
    const float* __restrict__ out_W, const float* __restrict__ out_b,
    float* __restrict__ out,
    ushort_t* __restrict__ value_bf, ushort_t* __restrict__ query_bf,
    ushort_t* __restrict__ vproj, ushort_t* __restrict__ qkcat,
    ushort_t* __restrict__ slots,
    ushort_t* __restrict__ value_Wt, ushort_t* __restrict__ out_Wt,
    ushort_t* __restrict__ qk_Wt) {
    cooperative_groups::grid_group grid = cooperative_groups::this_grid();
    __shared__ SmemAll sm;
    const int nb = gridDim.x;

    // ---- stage P: conversions + weight transpose ----
    for (int u = blockIdx.x; u < 5842; u += nb)
        prep_unit(u, &sm.p, value, query, value_W, out_W, off_W, attw_W,
                  value_bf, query_bf, value_Wt, out_Wt, qk_Wt);
    grid.sync();

    // ---- stage G1: value-proj (2040 tiles) + qk-proj (1884 tiles) ----
    for (int u = blockIdx.x; u < 3924; u += nb) {
        if (u < 2040)
            gemm64_tile<true, false>(&sm.g, value_bf, value_Wt, value_b, value_b,
                                     256, nullptr, (void*)vproj, 32640, 256, u);
        else
            gemm64_tile<true, false>(&sm.g, query_bf, qk_Wt, off_b, attw_b,
                                     512, nullptr, (void*)qkcat, 10000, 768, u - 2040);
    }
    grid.sync();

    // ---- stage S: deformable sampling ----
    for (int q = blockIdx.x; q < 10000; q += nb)
        sample_unit(q, &sm.s, qkcat, refp, vox, vproj, slots);
    grid.sync();

    // ---- stage G2: output projection + residual ----
    for (int u = blockIdx.x; u < 628; u += nb)
        gemm64_tile<false, true>(&sm.g, slots, out_Wt, out_b, out_b, 256,
                                 query, (void*)out, 10000, 256, u);
}

// ---------------------------------------------------------------------------
extern "C" void kernel_launch(void* const* d_in, const int* in_sizes, int n_in,
                              void* d_out, int out_size, void* d_ws, size_t ws_size,
                              hipStream_t stream) {
    const float* query   = (const float*)d_in[0];
    // d_in[1] = key : unused
    const float* value   = (const float*)d_in[2];
    const float* refp    = (const float*)d_in[3];
    const int*   vox     = (const int*)d_in[4];
    // d_in[5], d_in[6] : compile-time constants
    const float* value_W = (const float*)d_in[7];
    const float* value_b = (const float*)d_in[8];
    const float* off_W   = (const float*)d_in[9];
    const float* off_b   = (const float*)d_in[10];
    const float* attw_W  = (const float*)d_in[11];
    const float* attw_b  = (const float*)d_in[12];
    const float* out_W   = (const float*)d_in[13];
    const float* out_b   = (const float*)d_in[14];
    float* out = (float*)d_out;

    // ws layout (bytes), total 54,558,720 (proven ws_size >= 57.6 MB):
    //   [0,        16711680)  vproj bf16 [32640][256]
    //   [16711680, 33423360)  value_bf bf16 (stages P,G1) / slots bf16 (S,G2)
    //   [33423360, 48783360)  qkcat bf16 [10000][768]     (no alias: live in G1+S)
    //   [48783360, 53903360)  query_bf bf16
    //   [53903360, ...)       value_Wt | out_Wt | qk_Wt
    char* ws = (char*)d_ws;
    ushort_t* vproj    = (ushort_t*)(ws);
    ushort_t* value_bf = (ushort_t*)(ws + 16711680);
    ushort_t* slots    = (ushort_t*)(ws + 16711680);
    ushort_t* qkcat    = (ushort_t*)(ws + 33423360);
    ushort_t* query_bf = (ushort_t*)(ws + 48783360);
    ushort_t* value_Wt = (ushort_t*)(ws + 53903360);
    ushort_t* out_Wt   = (ushort_t*)(ws + 53903360 + 131072);
    ushort_t* qk_Wt    = (ushort_t*)(ws + 53903360 + 262144);

    int maxB = 0;
    hipError_t oe = hipOccupancyMaxActiveBlocksPerMultiprocessor(&maxB, fused_k, 256, 0);
    if (oe != hipSuccess || maxB < 1) maxB = 1;
    unsigned nblk = (unsigned)maxB * 256u;
    if (nblk > 1024u) nblk = 1024u;

    void* args[] = {
        (void*)&query, (void*)&value, (void*)&refp, (void*)&vox,
        (void*)&value_W, (void*)&value_b, (void*)&off_W, (void*)&off_b,
        (void*)&attw_W, (void*)&attw_b, (void*)&out_W, (void*)&out_b,
        (void*)&out,
        (void*)&value_bf, (void*)&query_bf, (void*)&vproj, (void*)&qkcat,
        (void*)&slots, (void*)&value_Wt, (void*)&out_Wt, (void*)&qk_Wt};
    hipLaunchCooperativeKernel((void*)fused_k, dim3(nblk), dim3(256),
                               args, 0, stream);
}

// Round 11
// 335.307 us; speedup vs baseline: 2.2663x; 2.2663x over previous
//
#include <hip/hip_runtime.h>

// ---------------------------------------------------------------------------
// SpatialSatCrossAttention (MS deformable attention, 6 cams, 10000 queries)
// ALL float tensors are float32 on the wire; vox int32.
// Launches (4):
//   1. prep_w    : weight mats -> Wt[n][k] bf16 (512 blocks)
//   2. gemm_vqk  : vproj = value @ value_W + b  (f32 A inline-cvt, bf16 out)
//                  qkcat = query @ [off|attw]_W (f32 A inline-cvt, f32 out)
//                  fused in one 984-block launch, compile-time branches
//   3. sample_k  : deformable bilinear sampling -> slots bf16
//                  (corner idx/w exchanged via __shfl, zero c-loop barriers)
//   4. gemm_out  : out = slots @ out_W + out_b + query (f32 d_out)
// GEMM body: 128x128 tile, 4 waves (2x2), 4x4 mfma_f32_16x16x32_bf16, BK=32,
// double-buffered LDS + register prefetch (R7-proven).
// ---------------------------------------------------------------------------

typedef unsigned short ushort_t;
typedef unsigned int uint_t;
typedef __attribute__((ext_vector_type(8))) short bf16x8;
typedef __attribute__((ext_vector_type(4))) float f32x4;
typedef __attribute__((ext_vector_type(2))) float f32x2;

__device__ __forceinline__ float bf2f(ushort_t u) {
    return __uint_as_float(((uint_t)u) << 16);
}
__device__ __forceinline__ ushort_t f2bf(float f) {
    uint_t i = __float_as_uint(f);
    uint_t r = i + 0x7fffu + ((i >> 16) & 1u);   // round-to-nearest-even
    return (ushort_t)(r >> 16);
}
__device__ __forceinline__ bf16x8 pack8(float4 v0, float4 v1) {
    return (bf16x8){
        (short)f2bf(v0.x), (short)f2bf(v0.y), (short)f2bf(v0.z), (short)f2bf(v0.w),
        (short)f2bf(v1.x), (short)f2bf(v1.y), (short)f2bf(v1.z), (short)f2bf(v1.w)};
}

// ---------------------------------------------------------------------------
// prep_w: weight transpose+convert only. W[k][N] f32 -> T[n][256] bf16.
// grid (8,16,4): z=0 value_W, z=1 out_W, z=2 off_W(512), z=3 attw_W.
// ---------------------------------------------------------------------------
__global__ __launch_bounds__(256) void prep_w(
    const float* __restrict__ Wv, const float* __restrict__ Wo,
    const float* __restrict__ Wf, const float* __restrict__ Wa,
    ushort_t* __restrict__ Tv, ushort_t* __restrict__ To,
    ushort_t* __restrict__ Tqk) {
    const int z = blockIdx.z;
    const float* W;
    ushort_t* T;
    int N;
    if (z == 0)      { W = Wv; T = Tv;              N = 256; }
    else if (z == 1) { W = Wo; T = To;              N = 256; }
    else if (z == 2) { W = Wf; T = Tqk;             N = 512; }
    else             { W = Wa; T = Tqk + 512 * 256; N = 256; }
    const int n0 = blockIdx.y * 32;
    if (n0 >= N) return;
    const int k0 = blockIdx.x * 32;

    __shared__ float tile[32][33];
    const int tx = threadIdx.x & 31;
    const int ty = threadIdx.x >> 5;   // 0..7
    #pragma unroll
    for (int r = 0; r < 4; ++r) {
        const int k = ty + r * 8;
        tile[k][tx] = W[(size_t)(k0 + k) * N + n0 + tx];
    }
    __syncthreads();
    #pragma unroll
    for (int r = 0; r < 4; ++r) {
        const int n = ty + r * 8;
        T[(size_t)(n0 + n) * 256 + k0 + tx] = f2bf(tile[tx][n]);
    }
}

// ---------------------------------------------------------------------------
// MFMA GEMM body (R7 structure): C[M,N] = A[M,256] @ Wt^T + bias (+resid).
// AF32: A is f32, converted to bf16 during LDS staging; else A is bf16.
// Wt bf16 [N][256]. N multiple of 128. 256 threads, 128x128 tile.
// ---------------------------------------------------------------------------
template <bool AF32, bool OUT_BF16, bool RESID>
__device__ __forceinline__ void gemm_body(
    ushort_t (*sA)[128][32], ushort_t (*sB)[128][32],
    const void* __restrict__ Av, const ushort_t* __restrict__ Wt,
    const float* __restrict__ bias0, const float* __restrict__ bias1, int split,
    const float* __restrict__ resid, void* __restrict__ Cv,
    int M, int N, int bx, int by) {
    const int m0 = bx * 128;
    const int n0 = by * 128;
    const int t    = threadIdx.x;
    const int lane = t & 63;
    const int w    = t >> 6;
    const int wr   = w >> 1, wc = w & 1;

    const int srow = t >> 2;          // 0..63
    const int skof = (t & 3) * 8;     // 0,8,16,24

    const bool am0 = (m0 + srow) < M;
    const bool am1 = (m0 + 64 + srow) < M;
    const float*    Af0 = (const float*)Av + (size_t)(m0 + srow) * 256 + skof;
    const float*    Af1 = Af0 + (size_t)64 * 256;
    const ushort_t* Ab0 = (const ushort_t*)Av + (size_t)(m0 + srow) * 256 + skof;
    const ushort_t* Ab1 = Ab0 + (size_t)64 * 256;
    const ushort_t* Bp0 = Wt + (size_t)(n0 + srow) * 256 + skof;
    const ushort_t* Bp1 = Bp0 + (size_t)64 * 256;

    const bf16x8 zz = {0, 0, 0, 0, 0, 0, 0, 0};

    auto loadA = [&](const float* af, const ushort_t* ab, int ko, bool ok) -> bf16x8 {
        if (!ok) return zz;
        if (AF32) {
            const float4 v0 = *(const float4*)(af + ko);
            const float4 v1 = *(const float4*)(af + ko + 4);
            return pack8(v0, v1);
        }
        return *(const bf16x8*)(ab + ko);
    };

    f32x4 acc[4][4];
    #pragma unroll
    for (int i = 0; i < 4; ++i)
        #pragma unroll
        for (int j = 0; j < 4; ++j)
            acc[i][j] = (f32x4){0.f, 0.f, 0.f, 0.f};

    // prologue: tile 0 -> LDS[0]
    {
        const bf16x8 a0 = loadA(Af0, Ab0, 0, am0);
        const bf16x8 a1 = loadA(Af1, Ab1, 0, am1);
        const bf16x8 b0 = *(const bf16x8*)(Bp0);
        const bf16x8 b1 = *(const bf16x8*)(Bp1);
        *(bf16x8*)(&sA[0][srow][skof])      = a0;
        *(bf16x8*)(&sA[0][64 + srow][skof]) = a1;
        *(bf16x8*)(&sB[0][srow][skof])      = b0;
        *(bf16x8*)(&sB[0][64 + srow][skof]) = b1;
    }
    __syncthreads();

    const int rl = lane & 15;
    const int kq = (lane >> 4) * 8;

    for (int k = 0; k < 8; ++k) {
        const int buf = k & 1;

        bf16x8 na0 = zz, na1 = zz, nb0 = zz, nb1 = zz;
        if (k < 7) {
            const int ko = (k + 1) * 32;
            na0 = loadA(Af0, Ab0, ko, am0);
            na1 = loadA(Af1, Ab1, ko, am1);
            nb0 = *(const bf16x8*)(Bp0 + ko);
            nb1 = *(const bf16x8*)(Bp1 + ko);
        }

        bf16x8 af[4], bfr[4];
        #pragma unroll
        for (int i = 0; i < 4; ++i)
            af[i] = *(const bf16x8*)(&sA[buf][wr * 64 + i * 16 + rl][kq]);
        #pragma unroll
        for (int j = 0; j < 4; ++j)
            bfr[j] = *(const bf16x8*)(&sB[buf][wc * 64 + j * 16 + rl][kq]);
        #pragma unroll
        for (int i = 0; i < 4; ++i)
            #pragma unroll
            for (int j = 0; j < 4; ++j)
                acc[i][j] = __builtin_amdgcn_mfma_f32_16x16x32_bf16(
                    af[i], bfr[j], acc[i][j], 0, 0, 0);

        if (k < 7) {
            __syncthreads();
            *(bf16x8*)(&sA[buf ^ 1][srow][skof])      = na0;
            *(bf16x8*)(&sA[buf ^ 1][64 + srow][skof]) = na1;
            *(bf16x8*)(&sB[buf ^ 1][srow][skof])      = nb0;
            *(bf16x8*)(&sB[buf ^ 1][64 + srow][skof]) = nb1;
            __syncthreads();
        }
    }

    // --- epilogue: C/D layout col=lane&15, row=(lane>>4)*4+reg (m89) ---
    const int col_l = lane & 15;
    const int rq    = (lane >> 4) * 4;
    #pragma unroll
    for (int j = 0; j < 4; ++j) {
        const int gn = n0 + wc * 64 + j * 16 + col_l;
        const float bj = (gn < split) ? bias0[gn] : bias1[gn - split];
        #pragma unroll
        for (int i = 0; i < 4; ++i) {
            #pragma unroll
            for (int r = 0; r < 4; ++r) {
                const int gm = m0 + wr * 64 + i * 16 + rq + r;
                if (gm >= M) continue;
                float v = acc[i][j][r] + bj;
                if (RESID) v += resid[(size_t)gm * N + gn];
                if (OUT_BF16)
                    ((ushort_t*)Cv)[(size_t)gm * N + gn] = f2bf(v);
                else
                    ((float*)Cv)[(size_t)gm * N + gn] = v;
            }
        }
    }
}

// Fused independent GEMMs: blocks [0,510) -> vproj, [510,984) -> qkcat.
__global__ __launch_bounds__(256) void gemm_vqk(
    const float* __restrict__ value, const ushort_t* __restrict__ value_Wt,
    const float* __restrict__ value_b, ushort_t* __restrict__ vproj,
    const float* __restrict__ query, const ushort_t* __restrict__ qk_Wt,
    const float* __restrict__ off_b, const float* __restrict__ attw_b,
    float* __restrict__ qkcat) {
    __shared__ ushort_t sA[2][128][32];
    __shared__ ushort_t sB[2][128][32];
    int b = blockIdx.x;
    if (b < 510) {
        gemm_body<true, true, false>(sA, sB, value, value_Wt, value_b, value_b,
                                     256, nullptr, (void*)vproj, 32640, 256,
                                     b % 255, b / 255);
    } else {
        b -= 510;
        gemm_body<true, false, false>(sA, sB, query, qk_Wt, off_b, attw_b,
                                      512, nullptr, (void*)qkcat, 10000, 768,
                                      b % 79, b / 79);
    }
}

__global__ __launch_bounds__(256) void gemm_out_k(
    const ushort_t* __restrict__ slots, const ushort_t* __restrict__ out_Wt,
    const float* __restrict__ out_b, const float* __restrict__ query,
    float* __restrict__ out) {
    __shared__ ushort_t sA[2][128][32];
    __shared__ ushort_t sB[2][128][32];
    gemm_body<false, false, true>(sA, sB, slots, out_Wt, out_b, out_b, 256,
                                  query, (void*)out, 10000, 256,
                                  blockIdx.x, blockIdx.y);
}

// ---------------------------------------------------------------------------
// Deformable sampling. 1 block per query, 256 threads.
//   setup role : (h, lp = tid&31)  -> corner idx/weights for its (h,lvl,p)
//   gather role: (h, slice, g)     -> 16B dwordx4 loads of 8 bf16 channels
// Corner (idx,w) exchanged via __shfl within the wave (setup lane for
// (h, slice*4+j) is (lane&32)+(slice*4+j)) -> no LDS tables, no barriers
// in the camera loop.  f32x2 accumulators (v_pk_fma_f32).
// ---------------------------------------------------------------------------
__global__ __launch_bounds__(256) void sample_k(
    const float* __restrict__ qkcat,    // [10000, 768]
    const float* __restrict__ refp,     // f32 [6,1,10000,4,2]
    const int* __restrict__ vox,        // int32 [6,1,10000,4]
    const ushort_t* __restrict__ vproj, // bf16 [6*5440, 256]
    ushort_t* __restrict__ slots) {     // bf16 [10000, 256]
    const int q   = blockIdx.x;
    const int tid = threadIdx.x;
    const int lane  = tid & 63;
    const int h     = tid >> 5;
    const int lp    = tid & 31;          // setup role
    const int slice = (tid >> 2) & 7;    // gather role
    const int g     = tid & 3;           // gather role: channels g*8..g*8+7

    __shared__ float s_valid[8];
    __shared__ float s_red[256][8];      // [tid][chan-in-group]

    if (tid < 6) {
        const int base = (tid * 10000 + q) * 4;
        const int mm = vox[base] | vox[base + 1] | vox[base + 2] | vox[base + 3];
        s_valid[tid] = mm ? 1.0f : 0.0f;
    }

    // ---- softmax over 32 (lvl,p) entries within each head ----
    const float a = qkcat[(size_t)q * 768 + 512 + tid];
    float mx = a;
    #pragma unroll
    for (int o = 16; o >= 1; o >>= 1) mx = fmaxf(mx, __shfl_xor(mx, o));
    const float e = __expf(a - mx);
    float se = e;
    #pragma unroll
    for (int o = 16; o >= 1; o >>= 1) se += __shfl_xor(se, o);
    const float aw = e / se;

    // ---- camera-independent part of this thread's sample location ----
    const int lvl = lp >> 3;
    const int p   = lp & 7;
    const int dd  = p & 3;
    const int   Sarr[4]   = {64, 32, 16, 8};
    const int   Lstart[4] = {0, 4096, 5120, 5376};
    const int   S  = Sarr[lvl];
    const float Sf = (float)S;
    const int   lstart = Lstart[lvl];
    const float ox = qkcat[(size_t)q * 768 + h * 64 + lvl * 16 + p * 2 + 0] / Sf;
    const float oy = qkcat[(size_t)q * 768 + h * 64 + lvl * 16 + p * 2 + 1] / Sf;

    __syncthreads();
    const float cnt = s_valid[0] + s_valid[1] + s_valid[2] +
                      s_valid[3] + s_valid[4] + s_valid[5];

    f32x2 acc2[4] = {{0.f, 0.f}, {0.f, 0.f}, {0.f, 0.f}, {0.f, 0.f}};
    const ushort_t* vp = vproj + (g << 3);
    const int srcbase = (lane & 32) + slice * 4;

    for (int c = 0; c < 6; ++c) {
        if (s_valid[c] == 0.0f) continue;   // block-uniform branch

        // ---- setup: this (h,lvl,p) sample's 4 corner indices + weights ----
        int   ci0, ci1, ci2, ci3;
        float cw0, cw1, cw2, cw3;
        {
            const int rbase = ((c * 10000 + q) * 4 + dd) * 2;
            const float rx = refp[rbase + 0];
            const float ry = refp[rbase + 1];
            const float x  = (rx + ox) * Sf - 0.5f;
            const float y  = (ry + oy) * Sf - 0.5f;
            const float x0 = floorf(x), y0 = floorf(y);
            int   ci[4];
            float cw[4];
            #pragma unroll
            for (int k = 0; k < 4; ++k) {
                const float cx = x0 + (float)(k & 1);
                const float cy = y0 + (float)(k >> 1);
                const float wgt = (1.0f - fabsf(x - cx)) * (1.0f - fabsf(y - cy));
                const bool ok = (cx >= 0.0f) & (cx < Sf) & (cy >= 0.0f) & (cy < Sf);
                const int xi = (int)fminf(fmaxf(cx, 0.0f), Sf - 1.0f);
                const int yi = (int)fminf(fmaxf(cy, 0.0f), Sf - 1.0f);
                ci[k] = (c * 5440 + lstart + yi * S + xi) * 256 + h * 32;
                cw[k] = ok ? wgt * aw : 0.0f;
            }
            ci0 = ci[0]; ci1 = ci[1]; ci2 = ci[2]; ci3 = ci[3];
            cw0 = cw[0]; cw1 = cw[1]; cw2 = cw[2]; cw3 = cw[3];
        }

        // ---- gather: 4 lp x 4 corners; idx/w via in-wave shuffle ----
        #pragma unroll
        for (int j = 0; j < 4; ++j) {
            const int src = srcbase + j;
            const int i0 = __shfl(ci0, src), i1 = __shfl(ci1, src);
            const int i2 = __shfl(ci2, src), i3 = __shfl(ci3, src);
            const uint4 v0 = *(const uint4*)(vp + i0);
            const uint4 v1 = *(const uint4*)(vp + i1);
            const uint4 v2 = *(const uint4*)(vp + i2);
            const uint4 v3 = *(const uint4*)(vp + i3);
            const float w0 = __shfl(cw0, src), w1 = __shfl(cw1, src);
            const float w2 = __shfl(cw2, src), w3 = __shfl(cw3, src);
            const f32x2 W0 = {w0, w0}, W1 = {w1, w1}, W2 = {w2, w2}, W3 = {w3, w3};
            acc2[0] += W0 * (f32x2){__uint_as_float(v0.x << 16), __uint_as_float(v0.x & 0xffff0000u)};
            acc2[1] += W0 * (f32x2){__uint_as_float(v0.y << 16), __uint_as_float(v0.y & 0xffff0000u)};
            acc2[2] += W0 * (f32x2){__uint_as_float(v0.z << 16), __uint_as_float(v0.z & 0xffff0000u)};
            acc2[3] += W0 * (f32x2){__uint_as_float(v0.w << 16), __uint_as_float(v0.w & 0xffff0000u)};
            acc2[0] += W1 * (f32x2){__uint_as_float(v1.x << 16), __uint_as_float(v1.x & 0xffff0000u)};
            acc2[1] += W1 * (f32x2){__uint_as_float(v1.y << 16), __uint_as_float(v1.y & 0xffff0000u)};
            acc2[2] += W1 * (f32x2){__uint_as_float(v1.z << 16), __uint_as_float(v1.z & 0xffff0000u)};
            acc2[3] += W1 * (f32x2){__uint_as_float(v1.w << 16), __uint_as_float(v1.w & 0xffff0000u)};
            acc2[0] += W2 * (f32x2){__uint_as_float(v2.x << 16), __uint_as_float(v2.x & 0xffff0000u)};
            acc2[1] += W2 * (f32x2){__uint_as_float(v2.y << 16), __uint_as_float(v2.y & 0xffff0000u)};
            acc2[2] += W2 * (f32x2){__uint_as_float(v2.z << 16), __uint_as_float(v2.z & 0xffff0000u)};
            acc2[3] += W2 * (f32x2){__uint_as_float(v2.w << 16), __uint_as_float(v2.w & 0xffff0000u)};
            acc2[0] += W3 * (f32x2){__uint_as_float(v3.x << 16), __uint_as_float(v3.x & 0xffff0000u)};
            acc2[1] += W3 * (f32x2){__uint_as_float(v3.y << 16), __uint_as_float(v3.y & 0xffff0000u)};
            acc2[2] += W3 * (f32x2){__uint_as_float(v3.z << 16), __uint_as_float(v3.z & 0xffff0000u)};
            acc2[3] += W3 * (f32x2){__uint_as_float(v3.w << 16), __uint_as_float(v3.w & 0xffff0000u)};
        }
    }

    // ---- cross-slice reduction ----
    #pragma unroll
    for (int n = 0; n < 4; ++n) {
        s_red[tid][2 * n]     = acc2[n].x;
        s_red[tid][2 * n + 1] = acc2[n].y;
    }
    __syncthreads();

    const int cch = tid & 31;
    float sum = 0.0f;
    #pragma unroll
    for (int s = 0; s < 8; ++s)
        sum += s_red[h * 32 + s * 4 + (cch >> 3)][cch & 7];

    slots[(size_t)q * 256 + tid] = f2bf(sum / fmaxf(cnt, 1.0f));
}

// ---------------------------------------------------------------------------
extern "C" void kernel_launch(void* const* d_in, const int* in_sizes, int n_in,
                              void* d_out, int out_size, void* d_ws, size_t ws_size,
                              hipStream_t stream) {
    const float* query   = (const float*)d_in[0];
    // d_in[1] = key : unused by the deformable-attention math
    const float* value   = (const float*)d_in[2];   // (6,5440,1,256) -> (32640,256)
    const float* refp    = (const float*)d_in[3];
    const int*   vox     = (const int*)d_in[4];
    // d_in[5] spatial_shapes, d_in[6] level_start_index : compile-time constants
    const float* value_W = (const float*)d_in[7];
    const float* value_b = (const float*)d_in[8];
    const float* off_W   = (const float*)d_in[9];
    const float* off_b   = (const float*)d_in[10];
    const float* attw_W  = (const float*)d_in[11];
    const float* attw_b  = (const float*)d_in[12];
    const float* out_W   = (const float*)d_in[13];
    const float* out_b   = (const float*)d_in[14];
    float* out = (float*)d_out;

    // ws layout (bytes):
    //   [0,        16711680)  vproj bf16 [32640][256]
    //   [16711680, 47431680)  qkcat f32 [10000][768]
    //   [47431680, 52551680)  slots bf16 [10000][256]
    //   [52551680, 53207040)  value_Wt | out_Wt | qk_Wt  bf16
    char* ws = (char*)d_ws;
    ushort_t* vproj    = (ushort_t*)ws;
    float*    qkcat    = (float*)   (ws + 16711680);
    ushort_t* slots    = (ushort_t*)(ws + 47431680);
    ushort_t* value_Wt = (ushort_t*)(ws + 52551680);
    ushort_t* out_Wt   = (ushort_t*)(ws + 52551680 + 131072);
    ushort_t* qk_Wt    = (ushort_t*)(ws + 52551680 + 262144);

    // 1. weight transpose+convert -> Wt[n][k] bf16
    prep_w<<<dim3(8, 16, 4), 256, 0, stream>>>(
        value_W, out_W, off_W, attw_W, value_Wt, out_Wt, qk_Wt);
    // 2. fused value-proj (bf16 out) + offset/attw-proj (f32 out), f32 A inline
    gemm_vqk<<<984, 256, 0, stream>>>(value, value_Wt, value_b, vproj,
                                      query, qk_Wt, off_b, attw_b, qkcat);
    // 3. deformable sampling + softmax + camera mask/count -> bf16 slots
    sample_k<<<10000, 256, 0, stream>>>(qkcat, refp, vox, vproj, slots);
    // 4. output projection + residual, f32 out
    gemm_out_k<<<dim3(79, 2), 256, 0, stream>>>(slots, out_Wt, out_b, query, out);
}